// Round 3
// baseline (12468.452 us; speedup 1.0000x reference)
//
#include <hip/hip_runtime.h>
#include <hip/hip_bf16.h>
#include <math.h>

// FADiTBlockS2: b=4, nlat=128, nlon=256, dim=256, H=8, DH=64, BNECK=128, NK=32
// Round 2 fix: vT/phi/gn are NTOK x 512 (134MB bf16) — round-1 slots were 67MB
// and overlapped => MSA branch corrupted. Now per-b processing: two 33.5MB
// slots (vT_b -> gn_b reuse; phi_b). u1 lives in d_out (flag dtype, in-place).

#define B_ 4
#define NLAT 128
#define NLON 256
#define NTOK (B_*NLAT*NLON)   // 131072

typedef __hip_bfloat16 bf16;

__device__ __forceinline__ float b2f(bf16 x){ return __bfloat162float(x); }
__device__ __forceinline__ bf16  f2b(float x){ return __float2bfloat16(x); }
__device__ __forceinline__ float gelu_f(float x){
  float x3 = x*x*x;
  return 0.5f*x*(1.0f + tanhf(0.7978845608028654f*(x + 0.044715f*x3)));
}
__device__ __forceinline__ float ldin(const void* p, size_t i, int flag){
  return flag ? b2f(((const bf16*)p)[i]) : ((const float*)p)[i];
}
__device__ __forceinline__ void stout(void* p, size_t i, int flag, float v){
  if (flag) ((bf16*)p)[i] = f2b(v); else ((float*)p)[i] = v;
}

// ---------------- dtype detection: lon_diff[1] == 2*pi/256 -----------------
__global__ void k_detect(const void* lon_diff, int* flag){
  const float c = 0.02454369260617026f;
  float asF = ((const float*)lon_diff)[1];
  float asB = b2f(((const bf16*)lon_diff)[1]);
  float ef = fabsf(asF - c), eb = fabsf(asB - c);
  if (!isfinite(ef)) ef = 1e30f;
  *flag = (eb < ef) ? 1 : 0;   // 1 = bf16 buffers, 0 = f32 buffers
}

// ---------------- convert one input to canonical f32 -----------------------
__global__ __launch_bounds__(256) void k_cvt(const void* __restrict__ src,
                                             float* __restrict__ dst, int n,
                                             const int* __restrict__ flag){
  int f = *flag;
  for (int i = blockIdx.x*256 + threadIdx.x; i < n; i += gridDim.x*256)
    dst[i] = ldin(src, i, f);
}

// ---------------- mod = scalar_cond @ adaLN_w + adaLN_b  (4 x 1536) --------
__global__ __launch_bounds__(256) void k_mod(const float* __restrict__ sc,
                                             const float* __restrict__ w,
                                             const float* __restrict__ bias,
                                             float* __restrict__ mod){
  int gid = blockIdx.x*256 + threadIdx.x;        // 6144 total
  int s = gid / 1536, j = gid % 1536;
  float acc = bias[j];
  for (int c = 0; c < 256; ++c) acc += sc[s*256+c] * w[c*1536+j];
  mod[gid] = acc;
}

// ---------------- lw = cos(lat)/mean(cos(lat)) -----------------------------
__global__ __launch_bounds__(128) void k_lw(const float* __restrict__ lat,
                                            float* __restrict__ lw){
  __shared__ float red[128];
  int i = threadIdx.x;
  float cv = cosf(lat[i]);
  red[i] = cv; __syncthreads();
  for (int s = 64; s > 0; s >>= 1){ if (i < s) red[i] += red[i+s]; __syncthreads(); }
  float mean = red[0] * (1.0f/128.0f);
  lw[i] = cv / mean;
}

// ---------------- um = LN(u)*(1+sc_msa)+sh_msa  (per token) ----------------
__global__ __launch_bounds__(256) void k_um(const void* __restrict__ u,
                                            const float* __restrict__ mod,
                                            bf16* __restrict__ um,
                                            const int* __restrict__ flag){
  __shared__ float red[256];
  int f = *flag;
  int t = blockIdx.x; int c = threadIdx.x;
  int b = t >> 15;
  float x = ldin(u, (size_t)t*256 + c, f);
  red[c] = x; __syncthreads();
  for (int s = 128; s > 0; s >>= 1){ if (c < s) red[c] += red[c+s]; __syncthreads(); }
  float mean = red[0] * (1.0f/256.0f);
  __syncthreads();
  float d = x - mean;
  red[c] = d*d; __syncthreads();
  for (int s = 128; s > 0; s >>= 1){ if (c < s) red[c] += red[c+s]; __syncthreads(); }
  float var = red[0] * (1.0f/256.0f);
  float y = d * rsqrtf(var + 1e-5f);
  y = y * (1.0f + mod[b*1536 + 256 + c]) + mod[b*1536 + c];
  um[(size_t)t*256 + c] = f2b(y);
}

// ---------------- redx[b,l,c] = (1/128) * sum_i um[b,i,l,c]*lw[i] ----------
__global__ __launch_bounds__(256) void k_redx(const bf16* __restrict__ um,
                                              const float* __restrict__ lw,
                                              float* __restrict__ redx){
  __shared__ float lws[128];
  int tid = threadIdx.x;
  if (tid < 128) lws[tid] = lw[tid];
  __syncthreads();
  int gid = blockIdx.x*256 + tid;                 // 262144 total
  int c = gid & 255; int l = (gid >> 8) & 255; int b = gid >> 16;
  float acc = 0.0f;
  for (int i = 0; i < 128; ++i)
    acc += b2f(um[(((size_t)(b*128 + i)*256 + l)*256) + c]) * lws[i];
  redx[gid] = acc * (1.0f/128.0f);
}

// ---------------- redy[b,i,c] = (1/256) * sum_l um[b,i,l,c] ----------------
__global__ __launch_bounds__(256) void k_redy(const bf16* __restrict__ um,
                                              float* __restrict__ redy){
  int gid = blockIdx.x*256 + threadIdx.x;         // 131072 total
  int c = gid & 255; int i = (gid >> 8) & 127; int b = gid >> 15;
  float acc = 0.0f;
  for (int l = 0; l < 256; ++l)
    acc += b2f(um[(((size_t)(b*128 + i)*256 + l)*256) + c]);
  redy[gid] = acc * (1.0f/256.0f);
}

// ---------------- generic row GEMM: C[r,:] = act(A[r,:] @ W + bias) --------
__global__ __launch_bounds__(256) void gemm_row(const float* __restrict__ A,
                                                const float* __restrict__ W,
                                                const float* __restrict__ bias,
                                                float* __restrict__ C,
                                                int K, int N, int act){
  __shared__ float As[256];
  int r = blockIdx.x; int tid = threadIdx.x;
  for (int k = tid; k < K; k += 256) As[k] = A[(size_t)r*K + k];
  __syncthreads();
  for (int n = tid; n < N; n += 256){
    float acc = bias ? bias[n] : 0.0f;
    for (int k = 0; k < K; ++k) acc += As[k] * W[(size_t)k*N + n];
    if (act == 1) acc = gelu_f(acc);
    C[(size_t)r*N + n] = acc;
  }
}

// ---------------- radial[h,i,j] = sum_k basis(d[i,j],k+1) * w[k,h] ---------
__global__ __launch_bounds__(256) void k_radial(const float* __restrict__ d,
                                                const float* __restrict__ w,
                                                float* __restrict__ rad, int n){
  int gid = blockIdx.x*256 + threadIdx.x;         // 8*n*n
  int nn = n*n;
  int h = gid / nn; int rem = gid % nn;
  float dv = d[rem];
  float safe = fmaxf(dv, 1e-6f);
  float acc = 0.0f;
  for (int k = 0; k < 32; ++k){
    float nk = (float)(k+1);
    float basis = (dv > 1e-6f) ? (sinf(dv*nk)/safe) : nk;
    acc += basis * w[k*8 + h];
  }
  rad[gid] = acc;    // [(h*n+i)*n+j]
}

// ---------------- attention weights: softmax(q.k * radial) -----------------
// one block per (b,h,i) row, blockDim = n
__global__ __launch_bounds__(256) void k_attn(const float* __restrict__ qk,
                                              const float* __restrict__ rad,
                                              float* __restrict__ kout, int n){
  extern __shared__ float sm[];          // qs[64] + red[n]
  float* qs = sm; float* red = sm + 64;
  int j = threadIdx.x;
  int bid = blockIdx.x; int i = bid % n; int h = (bid / n) & 7; int b = bid / (n*8);
  if (j < 64) qs[j] = qk[((size_t)(b*n + i))*1024 + h*64 + j];
  __syncthreads();
  float dot = 0.0f;
  const float* krow = qk + ((size_t)(b*n + j))*1024 + 512 + h*64;
  for (int d0 = 0; d0 < 64; ++d0) dot += qs[d0]*krow[d0];
  float s = dot * rad[((size_t)(h*n + i))*n + j];
  red[j] = s; __syncthreads();
  for (int st = n>>1; st > 0; st >>= 1){ if (j < st) red[j] = fmaxf(red[j], red[j+st]); __syncthreads(); }
  float mx = red[0]; __syncthreads();
  float e = expf(s - mx);
  red[j] = e; __syncthreads();
  for (int st = n>>1; st > 0; st >>= 1){ if (j < st) red[j] += red[j+st]; __syncthreads(); }
  float sum = red[0];
  kout[(size_t)bid*n + j] = e / sum;     // layout (b,h,i,j)
}

// ---------------- per-b v-projection into vT_b[h,i,l,c] --------------------
__global__ __launch_bounds__(256) void k_v(const bf16* __restrict__ um,
                                           const float* __restrict__ W,
                                           bf16* __restrict__ vT, int b){
  __shared__ float As[4][256];
  int t0 = blockIdx.x*4; int tid = threadIdx.x;      // t0 local in [0,32768)
  for (int idx = tid; idx < 4*256; idx += 256){
    int m = idx >> 8, c = idx & 255;
    As[m][c] = b2f(um[((size_t)b*32768 + t0 + m)*256 + c]);
  }
  __syncthreads();
  float acc[4][2] = {};
  for (int c = 0; c < 256; ++c){
    float w0 = W[(size_t)c*512 + tid];
    float w1 = W[(size_t)c*512 + tid + 256];
    #pragma unroll
    for (int m = 0; m < 4; ++m){ float a = As[m][c]; acc[m][0] += a*w0; acc[m][1] += a*w1; }
  }
  for (int m = 0; m < 4; ++m){
    int il = t0 + m; int i = il >> 8; int l = il & 255;
    #pragma unroll
    for (int p = 0; p < 2; ++p){
      int o = tid + p*256; int h = o >> 6; int cd = o & 63;
      vT[(((size_t)(h*128 + i)*256 + l)*64) + cd] = f2b(acc[m][p]);
    }
  }
}

// -------- per-b phi1[h,i,m,c] = sum_j ky[b,h,i,j]*vT_b[h,j,m,c] ------------
// block = (h, m), 128 threads (thread = i)
__global__ __launch_bounds__(128) void k_phi1(const float* __restrict__ ky,
                                              const bf16* __restrict__ vT,
                                              bf16* __restrict__ phi, int b){
  __shared__ float As[128][33];   // [i][jj] chunk of ky
  __shared__ float Bs[32][64];
  int tid = threadIdx.x;
  int bid = blockIdx.x; int m = bid & 255; int h = bid >> 8;
  const float* Ab = ky + ((size_t)(b*8 + h))*128*128;
  const bf16* Bb = vT + (size_t)h*128*16384 + m*64;
  float acc[64] = {};
  for (int jc = 0; jc < 128; jc += 32){
    for (int idx = tid; idx < 128*32; idx += 128){
      int r = idx >> 5, jj = idx & 31;
      As[r][jj] = Ab[(size_t)r*128 + jc + jj];
    }
    for (int idx = tid; idx < 32*64; idx += 128){
      int jj = idx >> 6, c = idx & 63;
      Bs[jj][c] = b2f(Bb[(size_t)(jc+jj)*16384 + c]);
    }
    __syncthreads();
    for (int jj = 0; jj < 32; ++jj){
      float a = As[tid][jj];
      #pragma unroll
      for (int c = 0; c < 64; ++c) acc[c] += a * Bs[jj][c];
    }
    __syncthreads();
  }
  bf16* outp = phi + (size_t)h*128*16384 + (size_t)tid*16384 + m*64;
  #pragma unroll
  for (int c = 0; c < 64; ++c) outp[c] = f2b(acc[c]);
}

// --- per-b phi2 + GroupNorm: gn_b[(i*256+l)*512 + h*64+c] ------------------
// block = (h, i), 256 threads (thread = l)
__global__ __launch_bounds__(256) void k_phi2(const float* __restrict__ kx,
                                              const bf16* __restrict__ phi,
                                              bf16* __restrict__ gn, int b){
  __shared__ float As[256][33];   // [l][jj] chunk of kx
  __shared__ float Bs[32][64];
  int tid = threadIdx.x;
  int bid = blockIdx.x; int i = bid & 127; int h = bid >> 7;
  const float* Ab = kx + ((size_t)(b*8 + h))*256*256;
  const bf16* Bb = phi + ((size_t)h*128 + i)*16384;
  float acc[64] = {};
  for (int mc = 0; mc < 256; mc += 32){
    for (int idx = tid; idx < 256*32; idx += 256){
      int r = idx >> 5, jj = idx & 31;
      As[r][jj] = Ab[(size_t)r*256 + mc + jj];
    }
    for (int idx = tid; idx < 32*64; idx += 256){
      int jj = idx >> 6, c = idx & 63;
      Bs[jj][c] = b2f(Bb[(size_t)(mc+jj)*64 + c]);
    }
    __syncthreads();
    for (int jj = 0; jj < 32; ++jj){
      float a = As[tid][jj];
      #pragma unroll
      for (int c = 0; c < 64; ++c) acc[c] += a * Bs[jj][c];
    }
    __syncthreads();
  }
  float s1 = 0.0f;
  #pragma unroll
  for (int c = 0; c < 64; ++c) s1 += acc[c];
  float mean = s1*(1.0f/64.0f);
  float s2 = 0.0f;
  #pragma unroll
  for (int c = 0; c < 64; ++c){ float d = acc[c]-mean; s2 += d*d; }
  float rstd = rsqrtf(s2*(1.0f/64.0f) + 1e-6f);
  bf16* outp = gn + (((size_t)i*256 + tid)*8 + h)*64;
  #pragma unroll
  for (int c = 0; c < 64; ++c) outp[c] = f2b((acc[c]-mean)*rstd);
}

// --------- per-b u1 = u + g_msa*(gn @ merge_w + merge_b) → d_out -----------
__global__ __launch_bounds__(256) void k_merge(const bf16* __restrict__ gn,
                                               const float* __restrict__ W,
                                               const float* __restrict__ bias,
                                               const float* __restrict__ mod,
                                               const void* __restrict__ u,
                                               void* __restrict__ outv,
                                               const int* __restrict__ flag, int b){
  __shared__ float As[4][512];
  int f = *flag;
  int t0 = blockIdx.x*4; int tid = threadIdx.x;    // local token
  for (int idx = tid; idx < 4*512; idx += 256){
    int m = idx >> 9, k = idx & 511;
    As[m][k] = b2f(gn[(size_t)(t0+m)*512 + k]);
  }
  __syncthreads();
  float acc[4] = {};
  for (int k = 0; k < 512; ++k){
    float w = W[(size_t)k*256 + tid];
    #pragma unroll
    for (int m = 0; m < 4; ++m) acc[m] += As[m][k]*w;
  }
  float bs = bias[tid];
  float g = mod[b*1536 + 512 + tid];
  for (int m = 0; m < 4; ++m){
    size_t o = ((size_t)b*32768 + t0 + m)*256 + tid;
    stout(outv, o, f, ldin(u, o, f) + g*(acc[m] + bs));
  }
}

// ---------------- fused LN2 + FFN + residual, in place on d_out ------------
// block = 32 tokens, 256 threads; hidden looped in 16 chunks of 64.
// Safe in-place: each block reads only its own 32 tokens (into LDS) before
// writing them.
__global__ __launch_bounds__(256) void k_ffn(const float* __restrict__ mod,
                                             const float* __restrict__ w1,
                                             const float* __restrict__ b1,
                                             const float* __restrict__ w2,
                                             const float* __restrict__ b2,
                                             void* __restrict__ outv,
                                             const int* __restrict__ flag){
  __shared__ float u2s[32][256];
  __shared__ float hs[32][64];
  __shared__ float r1[32][8], r2[32][8], mvs[32], rss[32];
  int f = *flag;
  int tid = threadIdx.x;
  int t0 = blockIdx.x*32; int b = t0 >> 15;
  for (int idx = tid; idx < 32*256; idx += 256){
    int m = idx >> 8, c = idx & 255;
    u2s[m][c] = ldin(outv, (size_t)(t0+m)*256 + c, f);   // u1
  }
  __syncthreads();
  {
    int m = tid >> 3, j = tid & 7;
    float s1 = 0.0f, s2 = 0.0f;
    for (int c = j; c < 256; c += 8){ float v = u2s[m][c]; s1 += v; s2 += v*v; }
    r1[m][j] = s1; r2[m][j] = s2;
  }
  __syncthreads();
  if (tid < 32){
    float s1 = 0.0f, s2 = 0.0f;
    for (int j = 0; j < 8; ++j){ s1 += r1[tid][j]; s2 += r2[tid][j]; }
    float mean = s1*(1.0f/256.0f);
    float var = s2*(1.0f/256.0f) - mean*mean;
    mvs[tid] = mean; rss[tid] = rsqrtf(var + 1e-5f);
  }
  __syncthreads();
  int mg = tid >> 6;
  int n0 = (tid & 63)*4;
  float resid[32];     // u1 values this thread writes later
  #pragma unroll
  for (int q = 0; q < 8; ++q){
    int m = mg*8 + q;
    #pragma unroll
    for (int p = 0; p < 4; ++p) resid[q*4+p] = u2s[m][n0+p];
  }
  __syncthreads();
  for (int idx = tid; idx < 32*256; idx += 256){
    int m = idx >> 8, c = idx & 255;
    float v = (u2s[m][c] - mvs[m])*rss[m];
    u2s[m][c] = v*(1.0f + mod[b*1536 + 1024 + c]) + mod[b*1536 + 768 + c];
  }
  __syncthreads();
  int khl = tid & 63;
  float acc[8][4] = {};
  for (int ch = 0; ch < 16; ++ch){
    float ha[8];
    float bb = b1[ch*64 + khl];
    #pragma unroll
    for (int q = 0; q < 8; ++q) ha[q] = bb;
    for (int k = 0; k < 256; ++k){
      float wv = w1[(size_t)k*1024 + ch*64 + khl];
      #pragma unroll
      for (int q = 0; q < 8; ++q) ha[q] += u2s[mg*8+q][k]*wv;
    }
    #pragma unroll
    for (int q = 0; q < 8; ++q) hs[mg*8+q][khl] = gelu_f(ha[q]);
    __syncthreads();
    for (int kh = 0; kh < 64; ++kh){
      float4 wv = *(const float4*)(w2 + (size_t)(ch*64 + kh)*256 + n0);
      #pragma unroll
      for (int q = 0; q < 8; ++q){
        float h = hs[mg*8+q][kh];
        acc[q][0] += h*wv.x; acc[q][1] += h*wv.y; acc[q][2] += h*wv.z; acc[q][3] += h*wv.w;
      }
    }
    __syncthreads();
  }
  for (int q = 0; q < 8; ++q){
    int m = mg*8 + q; size_t o = (size_t)(t0+m)*256 + n0;
    #pragma unroll
    for (int p = 0; p < 4; ++p){
      float g = mod[b*1536 + 1280 + n0 + p];
      float y = resid[q*4+p] + g*(acc[q][p] + b2[n0+p]);
      stout(outv, o+p, f, y);
    }
  }
}

extern "C" void kernel_launch(void* const* d_in, const int* in_sizes, int n_in,
                              void* d_out, int out_size, void* d_ws, size_t ws_size,
                              hipStream_t stream){
  (void)n_in; (void)out_size; (void)ws_size;

  char* p = (char*)d_ws;
  auto alloc = [&](size_t bytes)->void*{
    void* r = (void*)p; p += (bytes + 255) & ~(size_t)255; return r;
  };

  int* flag = (int*)alloc(4);

  // canonical f32 copies of inputs 1..27 (skip u = d_in[0])
  float* cin[28];
  cin[0] = nullptr;
  for (int i = 1; i < 28; ++i) cin[i] = (float*)alloc((size_t)in_sizes[i]*4);

  float* mod  = (float*)alloc((size_t)4*1536*4);
  float* lw   = (float*)alloc((size_t)128*4);
  float* redx = (float*)alloc((size_t)4*256*256*4);
  float* redy = (float*)alloc((size_t)4*128*256*4);
  float* tx   = (float*)alloc((size_t)4*256*256*4);
  float* hx   = (float*)alloc((size_t)4*256*256*4);
  float* uxb  = (float*)alloc((size_t)4*256*128*4);
  float* ty   = (float*)alloc((size_t)4*128*256*4);
  float* hy   = (float*)alloc((size_t)4*128*256*4);
  float* uyb  = (float*)alloc((size_t)4*128*128*4);
  float* qkx  = (float*)alloc((size_t)4*256*1024*4);
  float* qky  = (float*)alloc((size_t)4*128*1024*4);
  float* radx = (float*)alloc((size_t)8*256*256*4);
  float* rady = (float*)alloc((size_t)8*128*128*4);
  float* kxw  = (float*)alloc((size_t)4*8*256*256*4);
  float* kyw  = (float*)alloc((size_t)4*8*128*128*4);
  bf16* um    = (bf16*)alloc((size_t)NTOK*256*2);            // 67 MB
  bf16* slotV = (bf16*)alloc((size_t)8*128*256*64*2);        // 33.5 MB: vT_b -> gn_b
  bf16* slotP = (bf16*)alloc((size_t)8*128*256*64*2);        // 33.5 MB: phi_b

  const void* u = d_in[0];

  k_detect<<<1, 1, 0, stream>>>(d_in[3], flag);
  for (int i = 1; i < 28; ++i){
    int n = in_sizes[i];
    int blocks = (n + 255)/256; if (blocks > 1024) blocks = 1024;
    k_cvt<<<blocks, 256, 0, stream>>>(d_in[i], cin[i], n, flag);
  }

  k_mod<<<24, 256, 0, stream>>>(cin[4], cin[5], cin[6], mod);
  k_lw<<<1, 128, 0, stream>>>(cin[1], lw);
  k_um<<<NTOK, 256, 0, stream>>>(u, mod, um, flag);
  k_redx<<<1024, 256, 0, stream>>>(um, lw, redx);
  k_redy<<<512, 256, 0, stream>>>(um, redy);
  gemm_row<<<1024, 256, 0, stream>>>(redx, cin[8],  nullptr, tx,  256, 256, 0);
  gemm_row<<<1024, 256, 0, stream>>>(tx,   cin[9],  cin[10], hx,  256, 256, 1);
  gemm_row<<<1024, 256, 0, stream>>>(hx,   cin[11], cin[12], uxb, 256, 128, 0);
  gemm_row<<<1024, 256, 0, stream>>>(uxb,  cin[18], nullptr, qkx, 128, 1024, 0);
  gemm_row<<<512, 256, 0, stream>>>(redy, cin[13], nullptr, ty,  256, 256, 0);
  gemm_row<<<512, 256, 0, stream>>>(ty,   cin[14], cin[15], hy,  256, 256, 1);
  gemm_row<<<512, 256, 0, stream>>>(hy,   cin[16], cin[17], uyb, 256, 128, 0);
  gemm_row<<<512, 256, 0, stream>>>(uyb,  cin[19], nullptr, qky, 128, 1024, 0);
  k_radial<<<(8*256*256)/256, 256, 0, stream>>>(cin[3], cin[20], radx, 256);
  k_radial<<<(8*128*128)/256, 256, 0, stream>>>(cin[2], cin[21], rady, 128);
  k_attn<<<4*8*256, 256, (64+256)*4, stream>>>(qkx, radx, kxw, 256);
  k_attn<<<4*8*128, 128, (64+128)*4, stream>>>(qky, rady, kyw, 128);

  for (int b = 0; b < 4; ++b){
    bf16* vTb = slotV;
    bf16* phb = slotP;
    bf16* gnb = slotV;   // reuse: vT_b dead after k_phi1
    k_v   <<<8192, 256, 0, stream>>>(um, cin[7], vTb, b);
    k_phi1<<<8*256, 128, 0, stream>>>(kyw, vTb, phb, b);
    k_phi2<<<8*128, 256, 0, stream>>>(kxw, phb, gnb, b);
    k_merge<<<8192, 256, 0, stream>>>(gnb, cin[22], cin[23], mod, u, d_out, flag, b);
  }
  k_ffn<<<NTOK/32, 256, 0, stream>>>(mod, cin[24], cin[25], cin[26], cin[27], d_out, flag);
}

// Round 4
// 4984.853 us; speedup vs baseline: 2.5013x; 2.5013x over previous
//
#include <hip/hip_runtime.h>
#include <hip/hip_bf16.h>
#include <math.h>

// FADiTBlockS2: b=4, nlat=128, nlon=256, dim=256, H=8, DH=64, BNECK=128, NK=32
// Round 3: k_ffn (8.4ms, 67% of total, latency-bound f32) -> bf16 MFMA
// 16x16x32 with fragment-order packed weights. Everything else unchanged
// (passed at absmax 0.031).

#define B_ 4
#define NLAT 128
#define NLON 256
#define NTOK (B_*NLAT*NLON)   // 131072

typedef __hip_bfloat16 bf16;
typedef __attribute__((ext_vector_type(8))) short short8;
typedef __attribute__((ext_vector_type(4))) float f32x4;

__device__ __forceinline__ float b2f(bf16 x){ return __bfloat162float(x); }
__device__ __forceinline__ bf16  f2b(float x){ return __float2bfloat16(x); }
__device__ __forceinline__ unsigned short f2bits(float x){
  bf16 h = __float2bfloat16(x);
  return *(unsigned short*)&h;
}
__device__ __forceinline__ float gelu_f(float x){
  float x3 = x*x*x;
  return 0.5f*x*(1.0f + tanhf(0.7978845608028654f*(x + 0.044715f*x3)));
}
__device__ __forceinline__ float ldin(const void* p, size_t i, int flag){
  return flag ? b2f(((const bf16*)p)[i]) : ((const float*)p)[i];
}
__device__ __forceinline__ void stout(void* p, size_t i, int flag, float v){
  if (flag) ((bf16*)p)[i] = f2b(v); else ((float*)p)[i] = v;
}

// ---------------- dtype detection: lon_diff[1] == 2*pi/256 -----------------
__global__ void k_detect(const void* lon_diff, int* flag){
  const float c = 0.02454369260617026f;
  float asF = ((const float*)lon_diff)[1];
  float asB = b2f(((const bf16*)lon_diff)[1]);
  float ef = fabsf(asF - c), eb = fabsf(asB - c);
  if (!isfinite(ef)) ef = 1e30f;
  *flag = (eb < ef) ? 1 : 0;   // 1 = bf16 buffers, 0 = f32 buffers
}

// ---------------- convert one input to canonical f32 -----------------------
__global__ __launch_bounds__(256) void k_cvt(const void* __restrict__ src,
                                             float* __restrict__ dst, int n,
                                             const int* __restrict__ flag){
  int f = *flag;
  for (int i = blockIdx.x*256 + threadIdx.x; i < n; i += gridDim.x*256)
    dst[i] = ldin(src, i, f);
}

// ------- pack weight [K][N] f32 -> fragment-order bf16 for 16x16x32 MFMA ---
// wf[((nt*KS + ks)*64 + lane)*8 + j] = W[ks*32 + (lane>>4)*8 + j][nt*16 + (lane&15)]
__global__ __launch_bounds__(256) void k_wprep(const float* __restrict__ W,
                                               unsigned short* __restrict__ wf,
                                               int KS, int ldn, int total){
  int gid = blockIdx.x*256 + threadIdx.x;
  if (gid >= total) return;
  int j = gid & 7; int lane = (gid >> 3) & 63; int rest = gid >> 9;
  int ks = rest % KS; int nt = rest / KS;
  int k = ks*32 + (lane >> 4)*8 + j;
  int n = nt*16 + (lane & 15);
  wf[gid] = f2bits(W[(size_t)k*ldn + n]);
}

// ---------------- mod = scalar_cond @ adaLN_w + adaLN_b  (4 x 1536) --------
__global__ __launch_bounds__(256) void k_mod(const float* __restrict__ sc,
                                             const float* __restrict__ w,
                                             const float* __restrict__ bias,
                                             float* __restrict__ mod){
  int gid = blockIdx.x*256 + threadIdx.x;        // 6144 total
  int s = gid / 1536, j = gid % 1536;
  float acc = bias[j];
  for (int c = 0; c < 256; ++c) acc += sc[s*256+c] * w[c*1536+j];
  mod[gid] = acc;
}

// ---------------- lw = cos(lat)/mean(cos(lat)) -----------------------------
__global__ __launch_bounds__(128) void k_lw(const float* __restrict__ lat,
                                            float* __restrict__ lw){
  __shared__ float red[128];
  int i = threadIdx.x;
  float cv = cosf(lat[i]);
  red[i] = cv; __syncthreads();
  for (int s = 64; s > 0; s >>= 1){ if (i < s) red[i] += red[i+s]; __syncthreads(); }
  float mean = red[0] * (1.0f/128.0f);
  lw[i] = cv / mean;
}

// ---------------- um = LN(u)*(1+sc_msa)+sh_msa  (per token) ----------------
__global__ __launch_bounds__(256) void k_um(const void* __restrict__ u,
                                            const float* __restrict__ mod,
                                            bf16* __restrict__ um,
                                            const int* __restrict__ flag){
  __shared__ float red[256];
  int f = *flag;
  int t = blockIdx.x; int c = threadIdx.x;
  int b = t >> 15;
  float x = ldin(u, (size_t)t*256 + c, f);
  red[c] = x; __syncthreads();
  for (int s = 128; s > 0; s >>= 1){ if (c < s) red[c] += red[c+s]; __syncthreads(); }
  float mean = red[0] * (1.0f/256.0f);
  __syncthreads();
  float d = x - mean;
  red[c] = d*d; __syncthreads();
  for (int s = 128; s > 0; s >>= 1){ if (c < s) red[c] += red[c+s]; __syncthreads(); }
  float var = red[0] * (1.0f/256.0f);
  float y = d * rsqrtf(var + 1e-5f);
  y = y * (1.0f + mod[b*1536 + 256 + c]) + mod[b*1536 + c];
  um[(size_t)t*256 + c] = f2b(y);
}

// ---------------- redx[b,l,c] = (1/128) * sum_i um[b,i,l,c]*lw[i] ----------
__global__ __launch_bounds__(256) void k_redx(const bf16* __restrict__ um,
                                              const float* __restrict__ lw,
                                              float* __restrict__ redx){
  __shared__ float lws[128];
  int tid = threadIdx.x;
  if (tid < 128) lws[tid] = lw[tid];
  __syncthreads();
  int gid = blockIdx.x*256 + tid;                 // 262144 total
  int c = gid & 255; int l = (gid >> 8) & 255; int b = gid >> 16;
  float acc = 0.0f;
  for (int i = 0; i < 128; ++i)
    acc += b2f(um[(((size_t)(b*128 + i)*256 + l)*256) + c]) * lws[i];
  redx[gid] = acc * (1.0f/128.0f);
}

// ---------------- redy[b,i,c] = (1/256) * sum_l um[b,i,l,c] ----------------
__global__ __launch_bounds__(256) void k_redy(const bf16* __restrict__ um,
                                              float* __restrict__ redy){
  int gid = blockIdx.x*256 + threadIdx.x;         // 131072 total
  int c = gid & 255; int i = (gid >> 8) & 127; int b = gid >> 15;
  float acc = 0.0f;
  for (int l = 0; l < 256; ++l)
    acc += b2f(um[(((size_t)(b*128 + i)*256 + l)*256) + c]);
  redy[gid] = acc * (1.0f/256.0f);
}

// ---------------- generic row GEMM: C[r,:] = act(A[r,:] @ W + bias) --------
__global__ __launch_bounds__(256) void gemm_row(const float* __restrict__ A,
                                                const float* __restrict__ W,
                                                const float* __restrict__ bias,
                                                float* __restrict__ C,
                                                int K, int N, int act){
  __shared__ float As[256];
  int r = blockIdx.x; int tid = threadIdx.x;
  for (int k = tid; k < K; k += 256) As[k] = A[(size_t)r*K + k];
  __syncthreads();
  for (int n = tid; n < N; n += 256){
    float acc = bias ? bias[n] : 0.0f;
    for (int k = 0; k < K; ++k) acc += As[k] * W[(size_t)k*N + n];
    if (act == 1) acc = gelu_f(acc);
    C[(size_t)r*N + n] = acc;
  }
}

// ---------------- radial[h,i,j] = sum_k basis(d[i,j],k+1) * w[k,h] ---------
__global__ __launch_bounds__(256) void k_radial(const float* __restrict__ d,
                                                const float* __restrict__ w,
                                                float* __restrict__ rad, int n){
  int gid = blockIdx.x*256 + threadIdx.x;         // 8*n*n
  int nn = n*n;
  int h = gid / nn; int rem = gid % nn;
  float dv = d[rem];
  float safe = fmaxf(dv, 1e-6f);
  float acc = 0.0f;
  for (int k = 0; k < 32; ++k){
    float nk = (float)(k+1);
    float basis = (dv > 1e-6f) ? (sinf(dv*nk)/safe) : nk;
    acc += basis * w[k*8 + h];
  }
  rad[gid] = acc;    // [(h*n+i)*n+j]
}

// ---------------- attention weights: softmax(q.k * radial) -----------------
__global__ __launch_bounds__(256) void k_attn(const float* __restrict__ qk,
                                              const float* __restrict__ rad,
                                              float* __restrict__ kout, int n){
  extern __shared__ float sm[];          // qs[64] + red[n]
  float* qs = sm; float* red = sm + 64;
  int j = threadIdx.x;
  int bid = blockIdx.x; int i = bid % n; int h = (bid / n) & 7; int b = bid / (n*8);
  if (j < 64) qs[j] = qk[((size_t)(b*n + i))*1024 + h*64 + j];
  __syncthreads();
  float dot = 0.0f;
  const float* krow = qk + ((size_t)(b*n + j))*1024 + 512 + h*64;
  for (int d0 = 0; d0 < 64; ++d0) dot += qs[d0]*krow[d0];
  float s = dot * rad[((size_t)(h*n + i))*n + j];
  red[j] = s; __syncthreads();
  for (int st = n>>1; st > 0; st >>= 1){ if (j < st) red[j] = fmaxf(red[j], red[j+st]); __syncthreads(); }
  float mx = red[0]; __syncthreads();
  float e = expf(s - mx);
  red[j] = e; __syncthreads();
  for (int st = n>>1; st > 0; st >>= 1){ if (j < st) red[j] += red[j+st]; __syncthreads(); }
  float sum = red[0];
  kout[(size_t)bid*n + j] = e / sum;     // layout (b,h,i,j)
}

// ---------------- per-b v-projection into vT_b[h,i,l,c] --------------------
__global__ __launch_bounds__(256) void k_v(const bf16* __restrict__ um,
                                           const float* __restrict__ W,
                                           bf16* __restrict__ vT, int b){
  __shared__ float As[4][256];
  int t0 = blockIdx.x*4; int tid = threadIdx.x;      // t0 local in [0,32768)
  for (int idx = tid; idx < 4*256; idx += 256){
    int m = idx >> 8, c = idx & 255;
    As[m][c] = b2f(um[((size_t)b*32768 + t0 + m)*256 + c]);
  }
  __syncthreads();
  float acc[4][2] = {};
  for (int c = 0; c < 256; ++c){
    float w0 = W[(size_t)c*512 + tid];
    float w1 = W[(size_t)c*512 + tid + 256];
    #pragma unroll
    for (int m = 0; m < 4; ++m){ float a = As[m][c]; acc[m][0] += a*w0; acc[m][1] += a*w1; }
  }
  for (int m = 0; m < 4; ++m){
    int il = t0 + m; int i = il >> 8; int l = il & 255;
    #pragma unroll
    for (int p = 0; p < 2; ++p){
      int o = tid + p*256; int h = o >> 6; int cd = o & 63;
      vT[(((size_t)(h*128 + i)*256 + l)*64) + cd] = f2b(acc[m][p]);
    }
  }
}

// -------- per-b phi1[h,i,m,c] = sum_j ky[b,h,i,j]*vT_b[h,j,m,c] ------------
__global__ __launch_bounds__(128) void k_phi1(const float* __restrict__ ky,
                                              const bf16* __restrict__ vT,
                                              bf16* __restrict__ phi, int b){
  __shared__ float As[128][33];   // [i][jj] chunk of ky
  __shared__ float Bs[32][64];
  int tid = threadIdx.x;
  int bid = blockIdx.x; int m = bid & 255; int h = bid >> 8;
  const float* Ab = ky + ((size_t)(b*8 + h))*128*128;
  const bf16* Bb = vT + (size_t)h*128*16384 + m*64;
  float acc[64] = {};
  for (int jc = 0; jc < 128; jc += 32){
    for (int idx = tid; idx < 128*32; idx += 128){
      int r = idx >> 5, jj = idx & 31;
      As[r][jj] = Ab[(size_t)r*128 + jc + jj];
    }
    for (int idx = tid; idx < 32*64; idx += 128){
      int jj = idx >> 6, c = idx & 63;
      Bs[jj][c] = b2f(Bb[(size_t)(jc+jj)*16384 + c]);
    }
    __syncthreads();
    for (int jj = 0; jj < 32; ++jj){
      float a = As[tid][jj];
      #pragma unroll
      for (int c = 0; c < 64; ++c) acc[c] += a * Bs[jj][c];
    }
    __syncthreads();
  }
  bf16* outp = phi + (size_t)h*128*16384 + (size_t)tid*16384 + m*64;
  #pragma unroll
  for (int c = 0; c < 64; ++c) outp[c] = f2b(acc[c]);
}

// --- per-b phi2 + GroupNorm: gn_b[(i*256+l)*512 + h*64+c] ------------------
__global__ __launch_bounds__(256) void k_phi2(const float* __restrict__ kx,
                                              const bf16* __restrict__ phi,
                                              bf16* __restrict__ gn, int b){
  __shared__ float As[256][33];   // [l][jj] chunk of kx
  __shared__ float Bs[32][64];
  int tid = threadIdx.x;
  int bid = blockIdx.x; int i = bid & 127; int h = bid >> 7;
  const float* Ab = kx + ((size_t)(b*8 + h))*256*256;
  const bf16* Bb = phi + ((size_t)h*128 + i)*16384;
  float acc[64] = {};
  for (int mc = 0; mc < 256; mc += 32){
    for (int idx = tid; idx < 256*32; idx += 256){
      int r = idx >> 5, jj = idx & 31;
      As[r][jj] = Ab[(size_t)r*256 + mc + jj];
    }
    for (int idx = tid; idx < 32*64; idx += 256){
      int jj = idx >> 6, c = idx & 63;
      Bs[jj][c] = b2f(Bb[(size_t)(mc+jj)*64 + c]);
    }
    __syncthreads();
    for (int jj = 0; jj < 32; ++jj){
      float a = As[tid][jj];
      #pragma unroll
      for (int c = 0; c < 64; ++c) acc[c] += a * Bs[jj][c];
    }
    __syncthreads();
  }
  float s1 = 0.0f;
  #pragma unroll
  for (int c = 0; c < 64; ++c) s1 += acc[c];
  float mean = s1*(1.0f/64.0f);
  float s2 = 0.0f;
  #pragma unroll
  for (int c = 0; c < 64; ++c){ float d = acc[c]-mean; s2 += d*d; }
  float rstd = rsqrtf(s2*(1.0f/64.0f) + 1e-6f);
  bf16* outp = gn + (((size_t)i*256 + tid)*8 + h)*64;
  #pragma unroll
  for (int c = 0; c < 64; ++c) outp[c] = f2b((acc[c]-mean)*rstd);
}

// --------- per-b u1 = u + g_msa*(gn @ merge_w + merge_b) → d_out -----------
__global__ __launch_bounds__(256) void k_merge(const bf16* __restrict__ gn,
                                               const float* __restrict__ W,
                                               const float* __restrict__ bias,
                                               const float* __restrict__ mod,
                                               const void* __restrict__ u,
                                               void* __restrict__ outv,
                                               const int* __restrict__ flag, int b){
  __shared__ float As[4][512];
  int f = *flag;
  int t0 = blockIdx.x*4; int tid = threadIdx.x;    // local token
  for (int idx = tid; idx < 4*512; idx += 256){
    int m = idx >> 9, k = idx & 511;
    As[m][k] = b2f(gn[(size_t)(t0+m)*512 + k]);
  }
  __syncthreads();
  float acc[4] = {};
  for (int k = 0; k < 512; ++k){
    float w = W[(size_t)k*256 + tid];
    #pragma unroll
    for (int m = 0; m < 4; ++m) acc[m] += As[m][k]*w;
  }
  float bs = bias[tid];
  float g = mod[b*1536 + 512 + tid];
  for (int m = 0; m < 4; ++m){
    size_t o = ((size_t)b*32768 + t0 + m)*256 + tid;
    stout(outv, o, f, ldin(u, o, f) + g*(acc[m] + bs));
  }
}

// ======== MFMA fused LN2 + FFN + residual, in place on d_out ==============
// 64 tokens/block, 256 threads (4 waves, each owns 16 tokens end-to-end).
// w1f: [64 nt][8 ks][64 lane][8] bf16-bits; w2f: [16 nt][32 ks][64 lane][8].
__global__ __launch_bounds__(256) void k_ffn_mfma(
    const float* __restrict__ mod,
    const unsigned short* __restrict__ w1f,
    const float* __restrict__ b1c,
    const unsigned short* __restrict__ w2f,
    const float* __restrict__ b2c,
    void* __restrict__ outv,
    const int* __restrict__ flag){
  __shared__ __align__(16) unsigned short u2s[64][264];  // stride 528B = 33*16
  __shared__ __align__(16) unsigned short hs[64][136];   // stride 272B = 17*16
  __shared__ float smod_sh[256], smod_sc[256], smod_g[256];
  __shared__ float r1[64][4], r2[64][4], mv[64], rs[64];
  int f = *flag;
  int tid = threadIdx.x;
  int t0 = blockIdx.x*64; int bb = t0 >> 15;

  smod_sh[tid] = mod[bb*1536 + 768 + tid];
  smod_sc[tid] = mod[bb*1536 + 1024 + tid];
  smod_g[tid]  = mod[bb*1536 + 1280 + tid];

  // ---- LN stats: 4 threads per token ----
  int tok = tid >> 2, part = tid & 3;
  size_t base = ((size_t)(t0 + tok))*256 + part*64;
  float s1 = 0.0f, s2 = 0.0f;
  for (int c = 0; c < 64; ++c){
    float v = ldin(outv, base + c, f);
    s1 += v; s2 += v*v;
  }
  r1[tok][part] = s1; r2[tok][part] = s2;
  __syncthreads();
  if (part == 0){
    float a1 = r1[tok][0]+r1[tok][1]+r1[tok][2]+r1[tok][3];
    float a2 = r2[tok][0]+r2[tok][1]+r2[tok][2]+r2[tok][3];
    float mean = a1*(1.0f/256.0f);
    float var = a2*(1.0f/256.0f) - mean*mean;
    mv[tok] = mean; rs[tok] = rsqrtf(var + 1e-5f);
  }
  __syncthreads();
  // ---- modulated LN -> bf16 u2s ----
  {
    float mean = mv[tok], rstd = rs[tok];
    for (int c = 0; c < 64; ++c){
      int cc = part*64 + c;
      float v = ldin(outv, base + c, f);
      float y = (v - mean)*rstd*(1.0f + smod_sc[cc]) + smod_sh[cc];
      u2s[tok][cc] = f2bits(y);
    }
  }
  __syncthreads();

  // ---- MFMA: each wave owns 16 tokens ----
  int wave = tid >> 6, lane = tid & 63;
  int quad = lane >> 4, l15 = lane & 15;
  int mrow = wave*16;

  f32x4 acc2[16];
  #pragma unroll
  for (int nt = 0; nt < 16; ++nt) acc2[nt] = (f32x4){0.f,0.f,0.f,0.f};

  for (int hc = 0; hc < 8; ++hc){
    // GEMM1: S[16 tok][128 hid] = u2s @ w1[:, hc*128 .. +128]
    f32x4 acc1[8];
    #pragma unroll
    for (int nt = 0; nt < 8; ++nt) acc1[nt] = (f32x4){0.f,0.f,0.f,0.f};
    #pragma unroll
    for (int ks = 0; ks < 8; ++ks){
      short8 a = *(const short8*)&u2s[mrow + l15][ks*32 + quad*8];
      #pragma unroll
      for (int nt = 0; nt < 8; ++nt){
        short8 bfr = *(const short8*)&w1f[((((size_t)(hc*8 + nt))*8 + ks)*64 + lane)*8];
        acc1[nt] = __builtin_amdgcn_mfma_f32_16x16x32_bf16(a, bfr, acc1[nt], 0, 0, 0);
      }
    }
    // bias + gelu -> hs (wave-private rows)
    #pragma unroll
    for (int nt = 0; nt < 8; ++nt){
      int hid = nt*16 + l15;
      float bb1 = b1c[hc*128 + hid];
      #pragma unroll
      for (int r = 0; r < 4; ++r){
        int tokr = mrow + quad*4 + r;
        hs[tokr][hid] = f2bits(gelu_f(acc1[nt][r] + bb1));
      }
    }
    __syncthreads();
    // GEMM2 partial: acc2 += gelu_h @ w2[hc*128 .. +128, :]
    #pragma unroll
    for (int ks = 0; ks < 4; ++ks){
      short8 a2 = *(const short8*)&hs[mrow + l15][ks*32 + quad*8];
      #pragma unroll
      for (int nt = 0; nt < 16; ++nt){
        short8 bfr = *(const short8*)&w2f[((((size_t)nt)*32 + hc*4 + ks)*64 + lane)*8];
        acc2[nt] = __builtin_amdgcn_mfma_f32_16x16x32_bf16(a2, bfr, acc2[nt], 0, 0, 0);
      }
    }
    __syncthreads();
  }

  // ---- epilogue: out = u1 + g_mlp*(y + b2) ----
  #pragma unroll
  for (int nt = 0; nt < 16; ++nt){
    int n = nt*16 + l15;
    float g = smod_g[n];
    float bias = b2c[n];
    #pragma unroll
    for (int r = 0; r < 4; ++r){
      int tokr = t0 + mrow + quad*4 + r;
      size_t o = (size_t)tokr*256 + n;
      float y = ldin(outv, o, f) + g*(acc2[nt][r] + bias);
      stout(outv, o, f, y);
    }
  }
}

extern "C" void kernel_launch(void* const* d_in, const int* in_sizes, int n_in,
                              void* d_out, int out_size, void* d_ws, size_t ws_size,
                              hipStream_t stream){
  (void)n_in; (void)out_size; (void)ws_size;

  char* p = (char*)d_ws;
  auto alloc = [&](size_t bytes)->void*{
    void* r = (void*)p; p += (bytes + 255) & ~(size_t)255; return r;
  };

  int* flag = (int*)alloc(4);

  // canonical f32 copies of inputs 1..27 (skip u = d_in[0])
  float* cin[28];
  cin[0] = nullptr;
  for (int i = 1; i < 28; ++i) cin[i] = (float*)alloc((size_t)in_sizes[i]*4);

  float* mod  = (float*)alloc((size_t)4*1536*4);
  float* lw   = (float*)alloc((size_t)128*4);
  float* redx = (float*)alloc((size_t)4*256*256*4);
  float* redy = (float*)alloc((size_t)4*128*256*4);
  float* tx   = (float*)alloc((size_t)4*256*256*4);
  float* hx   = (float*)alloc((size_t)4*256*256*4);
  float* uxb  = (float*)alloc((size_t)4*256*128*4);
  float* ty   = (float*)alloc((size_t)4*128*256*4);
  float* hy   = (float*)alloc((size_t)4*128*256*4);
  float* uyb  = (float*)alloc((size_t)4*128*128*4);
  float* qkx  = (float*)alloc((size_t)4*256*1024*4);
  float* qky  = (float*)alloc((size_t)4*128*1024*4);
  float* radx = (float*)alloc((size_t)8*256*256*4);
  float* rady = (float*)alloc((size_t)8*128*128*4);
  float* kxw  = (float*)alloc((size_t)4*8*256*256*4);
  float* kyw  = (float*)alloc((size_t)4*8*128*128*4);
  unsigned short* w1f = (unsigned short*)alloc((size_t)256*1024*2);
  unsigned short* w2f = (unsigned short*)alloc((size_t)1024*256*2);
  bf16* um    = (bf16*)alloc((size_t)NTOK*256*2);            // 67 MB
  bf16* slotV = (bf16*)alloc((size_t)8*128*256*64*2);        // 33.5 MB: vT_b -> gn_b
  bf16* slotP = (bf16*)alloc((size_t)8*128*256*64*2);        // 33.5 MB: phi_b

  const void* u = d_in[0];

  k_detect<<<1, 1, 0, stream>>>(d_in[3], flag);
  for (int i = 1; i < 28; ++i){
    int n = in_sizes[i];
    int blocks = (n + 255)/256; if (blocks > 1024) blocks = 1024;
    k_cvt<<<blocks, 256, 0, stream>>>(d_in[i], cin[i], n, flag);
  }
  k_wprep<<<1024, 256, 0, stream>>>(cin[24], w1f, 8, 1024, 256*1024);   // ffn_w1
  k_wprep<<<1024, 256, 0, stream>>>(cin[26], w2f, 32, 256, 1024*256);   // ffn_w2

  k_mod<<<24, 256, 0, stream>>>(cin[4], cin[5], cin[6], mod);
  k_lw<<<1, 128, 0, stream>>>(cin[1], lw);
  k_um<<<NTOK, 256, 0, stream>>>(u, mod, um, flag);
  k_redx<<<1024, 256, 0, stream>>>(um, lw, redx);
  k_redy<<<512, 256, 0, stream>>>(um, redy);
  gemm_row<<<1024, 256, 0, stream>>>(redx, cin[8],  nullptr, tx,  256, 256, 0);
  gemm_row<<<1024, 256, 0, stream>>>(tx,   cin[9],  cin[10], hx,  256, 256, 1);
  gemm_row<<<1024, 256, 0, stream>>>(hx,   cin[11], cin[12], uxb, 256, 128, 0);
  gemm_row<<<1024, 256, 0, stream>>>(uxb,  cin[18], nullptr, qkx, 128, 1024, 0);
  gemm_row<<<512, 256, 0, stream>>>(redy, cin[13], nullptr, ty,  256, 256, 0);
  gemm_row<<<512, 256, 0, stream>>>(ty,   cin[14], cin[15], hy,  256, 256, 1);
  gemm_row<<<512, 256, 0, stream>>>(hy,   cin[16], cin[17], uyb, 256, 128, 0);
  gemm_row<<<512, 256, 0, stream>>>(uyb,  cin[19], nullptr, qky, 128, 1024, 0);
  k_radial<<<(8*256*256)/256, 256, 0, stream>>>(cin[3], cin[20], radx, 256);
  k_radial<<<(8*128*128)/256, 256, 0, stream>>>(cin[2], cin[21], rady, 128);
  k_attn<<<4*8*256, 256, (64+256)*4, stream>>>(qkx, radx, kxw, 256);
  k_attn<<<4*8*128, 128, (64+128)*4, stream>>>(qky, rady, kyw, 128);

  for (int b = 0; b < 4; ++b){
    bf16* vTb = slotV;
    bf16* phb = slotP;
    bf16* gnb = slotV;   // reuse: vT_b dead after k_phi1
    k_v   <<<8192, 256, 0, stream>>>(um, cin[7], vTb, b);
    k_phi1<<<8*256, 128, 0, stream>>>(kyw, vTb, phb, b);
    k_phi2<<<8*128, 256, 0, stream>>>(kxw, phb, gnb, b);
    k_merge<<<8192, 256, 0, stream>>>(gnb, cin[22], cin[23], mod, u, d_out, flag, b);
  }
  k_ffn_mfma<<<NTOK/64, 256, 0, stream>>>(mod, w1f, cin[25], w2f, cin[27], d_out, flag);
}

// Round 5
// 2951.817 us; speedup vs baseline: 4.2240x; 1.6887x over previous
//
#include <hip/hip_runtime.h>
#include <hip/hip_bf16.h>
#include <math.h>

// FADiTBlockS2: b=4, nlat=128, nlon=256, dim=256, H=8, DH=64, BNECK=128, NK=32
// Round 4: MFMA everywhere big. Verified frag pattern: A/B-frag = 16B load at
// [row(l15)][k = ks*32+quad*8 .. +8]; C/D: col = lane&15, row = quad*4+reg.
// MSA chain layouts chained so all stores are packed short4:
//   k_v2 (C^T per h)  -> vT[h][tok][c]
//   k_phi1b (C^T, A = 8x u16 gathers from vT, B = ky bf16) -> phi[h][i][c*256+m]
//   k_phi2b (A = phi rows m-fastest, B = kx bf16) -> OUTt[h][l][i*64+c]
//   k_gnb (coalesced GN over 64-c groups) -> gn[tok][h*64+c]
//   k_mergeb (C^T, A = WmT, B = gn rows) -> u1 in d_out
// k_ffn2/k_um2: coalesced LDS-tile LN phases (old per-lane scans were 95% of time).

#define B_ 4
#define NLAT 128
#define NLON 256
#define NTOK (B_*NLAT*NLON)   // 131072

typedef __hip_bfloat16 bf16;
typedef unsigned short u16;
typedef __attribute__((ext_vector_type(8))) short short8;
typedef __attribute__((ext_vector_type(4))) float f32x4;

__device__ __forceinline__ float b2f(bf16 x){ return __bfloat162float(x); }
__device__ __forceinline__ bf16  f2b(float x){ return __float2bfloat16(x); }
__device__ __forceinline__ u16 f2bits(float x){
  bf16 h = __float2bfloat16(x); return *(u16*)&h;
}
__device__ __forceinline__ float bits2f(u16 u){
  union { unsigned int i; float f; } v; v.i = ((unsigned int)u) << 16; return v.f;
}
__device__ __forceinline__ float gelu_f(float x){
  float x3 = x*x*x;
  return 0.5f*x*(1.0f + tanhf(0.7978845608028654f*(x + 0.044715f*x3)));
}
__device__ __forceinline__ float ldin(const void* p, size_t i, int flag){
  return flag ? b2f(((const bf16*)p)[i]) : ((const float*)p)[i];
}
__device__ __forceinline__ void stout(void* p, size_t i, int flag, float v){
  if (flag) ((bf16*)p)[i] = f2b(v); else ((float*)p)[i] = v;
}
__device__ __forceinline__ short4 pack4(float a, float b, float c, float d){
  short4 r; r.x = (short)f2bits(a); r.y = (short)f2bits(b);
  r.z = (short)f2bits(c); r.w = (short)f2bits(d); return r;
}

// ---------------- dtype detection: lon_diff[1] == 2*pi/256 -----------------
__global__ void k_detect(const void* lon_diff, int* flag){
  const float c = 0.02454369260617026f;
  float asF = ((const float*)lon_diff)[1];
  float asB = b2f(((const bf16*)lon_diff)[1]);
  float ef = fabsf(asF - c), eb = fabsf(asB - c);
  if (!isfinite(ef)) ef = 1e30f;
  *flag = (eb < ef) ? 1 : 0;   // 1 = bf16 buffers, 0 = f32 buffers
}

__global__ __launch_bounds__(256) void k_cvt(const void* __restrict__ src,
                                             float* __restrict__ dst, int n,
                                             const int* __restrict__ flag){
  int f = *flag;
  for (int i = blockIdx.x*256 + threadIdx.x; i < n; i += gridDim.x*256)
    dst[i] = ldin(src, i, f);
}

// ------- pack weight [K][N] f32 -> fragment-order bf16 (ffn weights) -------
__global__ __launch_bounds__(256) void k_wprep(const float* __restrict__ W,
                                               u16* __restrict__ wf,
                                               int KS, int ldn, int total){
  int gid = blockIdx.x*256 + threadIdx.x;
  if (gid >= total) return;
  int j = gid & 7; int lane = (gid >> 3) & 63; int rest = gid >> 9;
  int ks = rest % KS; int nt = rest / KS;
  int k = ks*32 + (lane >> 4)*8 + j;
  int n = nt*16 + (lane & 15);
  wf[gid] = f2bits(W[(size_t)k*ldn + n]);
}

// ------- transposed bf16 copy: WT[n][k] = W[k][n] ---------------------------
__global__ __launch_bounds__(256) void k_wtrans(const float* __restrict__ W,
                                                u16* __restrict__ WT, int K, int N){
  int gid = blockIdx.x*256 + threadIdx.x;
  if (gid >= K*N) return;
  int k = gid % K, n = gid / K;
  WT[(size_t)n*K + k] = f2bits(W[(size_t)k*N + n]);
}

// ---------------- mod = scalar_cond @ adaLN_w + adaLN_b  (4 x 1536) --------
__global__ __launch_bounds__(256) void k_mod(const float* __restrict__ sc,
                                             const float* __restrict__ w,
                                             const float* __restrict__ bias,
                                             float* __restrict__ mod){
  int gid = blockIdx.x*256 + threadIdx.x;
  int s = gid / 1536, j = gid % 1536;
  float acc = bias[j];
  for (int c = 0; c < 256; ++c) acc += sc[s*256+c] * w[c*1536+j];
  mod[gid] = acc;
}

// ---------------- lw = cos(lat)/mean(cos(lat)) -----------------------------
__global__ __launch_bounds__(128) void k_lw(const float* __restrict__ lat,
                                            float* __restrict__ lw){
  __shared__ float red[128];
  int i = threadIdx.x;
  float cv = cosf(lat[i]);
  red[i] = cv; __syncthreads();
  for (int s = 64; s > 0; s >>= 1){ if (i < s) red[i] += red[i+s]; __syncthreads(); }
  float mean = red[0] * (1.0f/128.0f);
  lw[i] = cv / mean;
}

// ------- um = LN(u)*(1+sc_msa)+sh_msa : 64 tokens/block, coalesced ---------
__global__ __launch_bounds__(256) void k_um2(const void* __restrict__ u,
                                             const float* __restrict__ mod,
                                             u16* __restrict__ um,
                                             const int* __restrict__ flag){
  __shared__ u16 tile[64][264];
  __shared__ float r1[64][4], r2[64][4], mv[64], rs[64];
  __shared__ float ssh[256], ssc[256];
  int f = *flag; int tid = threadIdx.x;
  int t0 = blockIdx.x*64; int b = t0 >> 15;
  ssh[tid] = mod[b*1536 + tid];
  ssc[tid] = mod[b*1536 + 256 + tid];
  // phase 1: coalesced load -> bf16 tile
  for (int it = 0; it < 16; ++it){
    int idx = it*256 + tid;       // 4096 vec4 groups
    int tok = idx >> 6, c4 = idx & 63;
    short4 v4;
    if (f){
      v4 = *(const short4*)((const bf16*)u + ((size_t)(t0+tok))*256 + c4*4);
    } else {
      float4 fv = ((const float4*)u)[((size_t)(t0+tok))*64 + c4];
      v4 = pack4(fv.x, fv.y, fv.z, fv.w);
    }
    *(short4*)&tile[tok][c4*4] = v4;
  }
  __syncthreads();
  // phase 2: stats (4 threads per token)
  {
    int tok = tid >> 2, part = tid & 3;
    float s1 = 0.f, s2 = 0.f;
    for (int c4 = 0; c4 < 16; ++c4){
      short4 v4 = *(const short4*)&tile[tok][part*64 + c4*4];
      float a = bits2f((u16)v4.x), bb = bits2f((u16)v4.y),
            c = bits2f((u16)v4.z), d = bits2f((u16)v4.w);
      s1 += a+bb+c+d; s2 += a*a+bb*bb+c*c+d*d;
    }
    r1[tok][part] = s1; r2[tok][part] = s2;
  }
  __syncthreads();
  if ((tid & 3) == 0){
    int tok = tid >> 2;
    float a1 = r1[tok][0]+r1[tok][1]+r1[tok][2]+r1[tok][3];
    float a2 = r2[tok][0]+r2[tok][1]+r2[tok][2]+r2[tok][3];
    float mean = a1*(1.0f/256.0f);
    float var = a2*(1.0f/256.0f) - mean*mean;
    mv[tok] = mean; rs[tok] = rsqrtf(var + 1e-5f);
  }
  __syncthreads();
  // phase 3: modulate + coalesced store
  for (int it = 0; it < 16; ++it){
    int idx = it*256 + tid;
    int tok = idx >> 6, c4 = idx & 63;
    float mean = mv[tok], rstd = rs[tok];
    short4 v4 = *(const short4*)&tile[tok][c4*4];
    float y[4]; u16 raw[4] = {(u16)v4.x,(u16)v4.y,(u16)v4.z,(u16)v4.w};
    #pragma unroll
    for (int p = 0; p < 4; ++p){
      int c = c4*4 + p;
      y[p] = (bits2f(raw[p]) - mean)*rstd*(1.0f + ssc[c]) + ssh[c];
    }
    *(short4*)(um + ((size_t)(t0+tok))*256 + c4*4) = pack4(y[0],y[1],y[2],y[3]);
  }
}

// ---------------- redx[b,l,c] = (1/128) * sum_i um[b,i,l,c]*lw[i] ----------
__global__ __launch_bounds__(256) void k_redx(const u16* __restrict__ um,
                                              const float* __restrict__ lw,
                                              float* __restrict__ redx){
  __shared__ float lws[128];
  int tid = threadIdx.x;
  if (tid < 128) lws[tid] = lw[tid];
  __syncthreads();
  int gid = blockIdx.x*256 + tid;
  int c = gid & 255; int l = (gid >> 8) & 255; int b = gid >> 16;
  float acc = 0.0f;
  for (int i = 0; i < 128; ++i)
    acc += bits2f(um[(((size_t)(b*128 + i)*256 + l)*256) + c]) * lws[i];
  redx[gid] = acc * (1.0f/128.0f);
}

__global__ __launch_bounds__(256) void k_redy(const u16* __restrict__ um,
                                              float* __restrict__ redy){
  int gid = blockIdx.x*256 + threadIdx.x;
  int c = gid & 255; int i = (gid >> 8) & 127; int b = gid >> 15;
  float acc = 0.0f;
  for (int l = 0; l < 256; ++l)
    acc += bits2f(um[(((size_t)(b*128 + i)*256 + l)*256) + c]);
  redy[gid] = acc * (1.0f/256.0f);
}

// ---------------- generic row GEMM (tiny bottleneck chain) -----------------
__global__ __launch_bounds__(256) void gemm_row(const float* __restrict__ A,
                                                const float* __restrict__ W,
                                                const float* __restrict__ bias,
                                                float* __restrict__ C,
                                                int K, int N, int act){
  __shared__ float As[256];
  int r = blockIdx.x; int tid = threadIdx.x;
  for (int k = tid; k < K; k += 256) As[k] = A[(size_t)r*K + k];
  __syncthreads();
  for (int n = tid; n < N; n += 256){
    float acc = bias ? bias[n] : 0.0f;
    for (int k = 0; k < K; ++k) acc += As[k] * W[(size_t)k*N + n];
    if (act == 1) acc = gelu_f(acc);
    C[(size_t)r*N + n] = acc;
  }
}

// ---------------- radial[h,i,j] ---------------------------------------------
__global__ __launch_bounds__(256) void k_radial(const float* __restrict__ d,
                                                const float* __restrict__ w,
                                                float* __restrict__ rad, int n){
  int gid = blockIdx.x*256 + threadIdx.x;
  int nn = n*n;
  int h = gid / nn; int rem = gid % nn;
  float dv = d[rem];
  float safe = fmaxf(dv, 1e-6f);
  float acc = 0.0f;
  for (int k = 0; k < 32; ++k){
    float nk = (float)(k+1);
    float basis = (dv > 1e-6f) ? (sinf(dv*nk)/safe) : nk;
    acc += basis * w[k*8 + h];
  }
  rad[gid] = acc;
}

// ---------------- attention weights -> bf16 rows [bh][i][j] ----------------
__global__ __launch_bounds__(256) void k_attn(const float* __restrict__ qk,
                                              const float* __restrict__ rad,
                                              u16* __restrict__ kout, int n){
  extern __shared__ float sm[];
  float* qs = sm; float* red = sm + 64;
  int j = threadIdx.x;
  int bid = blockIdx.x; int i = bid % n; int h = (bid / n) & 7; int b = bid / (n*8);
  if (j < 64) qs[j] = qk[((size_t)(b*n + i))*1024 + h*64 + j];
  __syncthreads();
  float dot = 0.0f;
  const float* krow = qk + ((size_t)(b*n + j))*1024 + 512 + h*64;
  for (int d0 = 0; d0 < 64; ++d0) dot += qs[d0]*krow[d0];
  float s = dot * rad[((size_t)(h*n + i))*n + j];
  red[j] = s; __syncthreads();
  for (int st = n>>1; st > 0; st >>= 1){ if (j < st) red[j] = fmaxf(red[j], red[j+st]); __syncthreads(); }
  float mx = red[0]; __syncthreads();
  float e = expf(s - mx);
  red[j] = e; __syncthreads();
  for (int st = n>>1; st > 0; st >>= 1){ if (j < st) red[j] += red[j+st]; __syncthreads(); }
  float sum = red[0];
  kout[(size_t)bid*n + j] = f2bits(e / sum);
}

// ======== k_v2: per-b v-proj, C^T form. M=512 hc, N=64 tokens, K=256 =======
__global__ __launch_bounds__(256) void k_v2(const u16* __restrict__ um,
                                            const u16* __restrict__ WvT,
                                            u16* __restrict__ vT, int b){
  int tid = threadIdx.x;
  int wave = tid>>6, lane = tid&63, quad = lane>>4, l15 = lane&15;
  int t0 = blockIdx.x*64;
  const u16* umb = um + ((size_t)b*32768 + t0)*256;
  f32x4 acc[8][4];
  #pragma unroll
  for (int mt = 0; mt < 8; ++mt)
    #pragma unroll
    for (int nt = 0; nt < 4; ++nt) acc[mt][nt] = (f32x4){0.f,0.f,0.f,0.f};
  for (int ks = 0; ks < 8; ++ks){
    short8 bfr[4];
    #pragma unroll
    for (int nt = 0; nt < 4; ++nt)
      bfr[nt] = *(const short8*)(umb + (size_t)(nt*16 + l15)*256 + ks*32 + quad*8);
    #pragma unroll
    for (int mt = 0; mt < 8; ++mt){
      short8 a = *(const short8*)(WvT + (size_t)((wave*8+mt)*16 + l15)*256 + ks*32 + quad*8);
      #pragma unroll
      for (int nt = 0; nt < 4; ++nt)
        acc[mt][nt] = __builtin_amdgcn_mfma_f32_16x16x32_bf16(a, bfr[nt], acc[mt][nt], 0, 0, 0);
    }
  }
  #pragma unroll
  for (int mt = 0; mt < 8; ++mt){
    int hc0 = (wave*8+mt)*16 + quad*4;
    int h = hc0 >> 6, c0 = hc0 & 63;
    #pragma unroll
    for (int nt = 0; nt < 4; ++nt){
      int tok = t0 + nt*16 + l15;
      *(short4*)(vT + (size_t)h*2097152 + (size_t)tok*64 + c0)
        = pack4(acc[mt][nt][0], acc[mt][nt][1], acc[mt][nt][2], acc[mt][nt][3]);
    }
  }
}

// ======== k_phi1b: C^T. M=(c,m) 16384, N=i 128, K=j 128 ====================
// A = v gathers (8x u16, stride 32KB, L2), B = ky bf16 rows. Out: phi[h][i][c*256+m]
__global__ __launch_bounds__(256) void k_phi1b(const u16* __restrict__ kyb,
                                               const u16* __restrict__ vT,
                                               u16* __restrict__ phi, int b){
  int tid = threadIdx.x;
  int wave = tid>>6, lane = tid&63, quad = lane>>4, l15 = lane&15;
  int bid = blockIdx.x; int mblk = bid & 63, h = bid >> 6;
  int m0 = mblk*256;
  const u16* vTh = vT + (size_t)h*2097152;
  const u16* kyh = kyb + (size_t)(b*8+h)*16384;
  f32x4 acc[4][8];
  #pragma unroll
  for (int mt = 0; mt < 4; ++mt)
    #pragma unroll
    for (int nt = 0; nt < 8; ++nt) acc[mt][nt] = (f32x4){0.f,0.f,0.f,0.f};
  for (int ks = 0; ks < 4; ++ks){
    short8 bfr[8];
    #pragma unroll
    for (int nt = 0; nt < 8; ++nt)
      bfr[nt] = *(const short8*)(kyh + (size_t)(nt*16 + l15)*128 + ks*32 + quad*8);
    #pragma unroll
    for (int mt = 0; mt < 4; ++mt){
      int cm = m0 + (wave*4+mt)*16 + l15;
      int c = cm >> 8, m = cm & 255;
      const u16* gp = vTh + ((size_t)(ks*32 + quad*8)*256 + m)*64 + c;
      short8 a;
      #pragma unroll
      for (int jj = 0; jj < 8; ++jj) ((u16*)&a)[jj] = gp[(size_t)jj*16384];
      #pragma unroll
      for (int nt = 0; nt < 8; ++nt)
        acc[mt][nt] = __builtin_amdgcn_mfma_f32_16x16x32_bf16(a, bfr[nt], acc[mt][nt], 0, 0, 0);
    }
  }
  #pragma unroll
  for (int mt = 0; mt < 4; ++mt){
    int cmr = m0 + (wave*4+mt)*16 + quad*4;
    #pragma unroll
    for (int nt = 0; nt < 8; ++nt){
      int i = nt*16 + l15;
      *(short4*)(phi + (size_t)h*2097152 + (size_t)i*16384 + cmr)
        = pack4(acc[mt][nt][0], acc[mt][nt][1], acc[mt][nt][2], acc[mt][nt][3]);
    }
  }
}

// ======== k_phi2b: M=(i,c) 8192, N=l 256, K=m 256 ==========================
// A = phi rows (m-fastest), B = kx bf16 rows. Out: OUTt[h][l][i*64+c]
__global__ __launch_bounds__(256) void k_phi2b(const u16* __restrict__ kxb,
                                               const u16* __restrict__ phi,
                                               u16* __restrict__ OUTt, int b){
  int tid = threadIdx.x;
  int wave = tid>>6, lane = tid&63, quad = lane>>4, l15 = lane&15;
  int bid = blockIdx.x; int mblk = bid & 63, h = bid >> 6;
  int m0 = mblk*128;
  int mhalf = (wave&1)*4, nhalf = (wave>>1)*8;
  const u16* ph = phi + (size_t)h*2097152;
  const u16* kxh = kxb + (size_t)(b*8+h)*65536;
  f32x4 acc[4][8];
  #pragma unroll
  for (int mt = 0; mt < 4; ++mt)
    #pragma unroll
    for (int nt = 0; nt < 8; ++nt) acc[mt][nt] = (f32x4){0.f,0.f,0.f,0.f};
  for (int ks = 0; ks < 8; ++ks){
    short8 bfr[8];
    #pragma unroll
    for (int nt = 0; nt < 8; ++nt)
      bfr[nt] = *(const short8*)(kxh + (size_t)((nhalf+nt)*16 + l15)*256 + ks*32 + quad*8);
    #pragma unroll
    for (int mt = 0; mt < 4; ++mt){
      int m2 = m0 + (mhalf+mt)*16 + l15;
      short8 a = *(const short8*)(ph + (size_t)m2*256 + ks*32 + quad*8);
      #pragma unroll
      for (int nt = 0; nt < 8; ++nt)
        acc[mt][nt] = __builtin_amdgcn_mfma_f32_16x16x32_bf16(a, bfr[nt], acc[mt][nt], 0, 0, 0);
    }
  }
  #pragma unroll
  for (int mt = 0; mt < 4; ++mt){
    int m2r = m0 + (mhalf+mt)*16 + quad*4;
    #pragma unroll
    for (int nt = 0; nt < 8; ++nt){
      int l = (nhalf+nt)*16 + l15;
      *(short4*)(OUTt + (size_t)h*2097152 + (size_t)l*8192 + m2r)
        = pack4(acc[mt][nt][0], acc[mt][nt][1], acc[mt][nt][2], acc[mt][nt][3]);
    }
  }
}

// ======== k_gnb: GroupNorm over 64-c groups, coalesced ======================
// OUTt[h][l][i*64+c] -> gn[(i*256+l)][h*64+c]
__global__ __launch_bounds__(256) void k_gnb(const u16* __restrict__ OUTt,
                                             u16* __restrict__ gn){
  int tid = threadIdx.x;
  int bid = blockIdx.x; int l = bid & 255, h = bid >> 8;
  int i = tid >> 1, half = tid & 1;
  const u16* src = OUTt + (size_t)h*2097152 + (size_t)l*8192 + i*64 + half*32;
  float v[32]; float s1 = 0.f, s2 = 0.f;
  #pragma unroll
  for (int c4 = 0; c4 < 8; ++c4){
    short4 v4 = *(const short4*)(src + c4*4);
    v[c4*4+0] = bits2f((u16)v4.x); v[c4*4+1] = bits2f((u16)v4.y);
    v[c4*4+2] = bits2f((u16)v4.z); v[c4*4+3] = bits2f((u16)v4.w);
  }
  #pragma unroll
  for (int c = 0; c < 32; ++c){ s1 += v[c]; s2 += v[c]*v[c]; }
  s1 += __shfl_xor(s1, 1); s2 += __shfl_xor(s2, 1);
  float mean = s1*(1.0f/64.0f);
  float var = s2*(1.0f/64.0f) - mean*mean;
  float rstd = rsqrtf(var + 1e-6f);
  u16* dst = gn + ((size_t)(i*256 + l))*512 + h*64 + half*32;
  #pragma unroll
  for (int c4 = 0; c4 < 8; ++c4)
    *(short4*)(dst + c4*4) = pack4((v[c4*4+0]-mean)*rstd, (v[c4*4+1]-mean)*rstd,
                                   (v[c4*4+2]-mean)*rstd, (v[c4*4+3]-mean)*rstd);
}

// ======== k_mergeb: C^T. M=d 256, N=128 tokens, K=512 ======================
__global__ __launch_bounds__(256) void k_mergeb(const u16* __restrict__ gn,
                                                const u16* __restrict__ WmT,
                                                const float* __restrict__ biasm,
                                                const float* __restrict__ mod,
                                                const void* __restrict__ u,
                                                void* __restrict__ outv,
                                                const int* __restrict__ flag, int b){
  __shared__ float smg[256], sbb[256];
  int f = *flag;
  int tid = threadIdx.x;
  smg[tid] = mod[b*1536 + 512 + tid];
  sbb[tid] = biasm[tid];
  __syncthreads();
  int wave = tid>>6, lane = tid&63, quad = lane>>4, l15 = lane&15;
  int t0 = blockIdx.x*128;
  int nt0 = wave*2;
  f32x4 acc[16][2];
  #pragma unroll
  for (int mt = 0; mt < 16; ++mt){ acc[mt][0] = (f32x4){0.f,0.f,0.f,0.f}; acc[mt][1] = (f32x4){0.f,0.f,0.f,0.f}; }
  for (int ks = 0; ks < 16; ++ks){
    short8 bfr[2];
    #pragma unroll
    for (int nti = 0; nti < 2; ++nti){
      int tok = t0 + (nt0+nti)*16 + l15;
      bfr[nti] = *(const short8*)(gn + (size_t)tok*512 + ks*32 + quad*8);
    }
    #pragma unroll
    for (int mt = 0; mt < 16; ++mt){
      short8 a = *(const short8*)(WmT + (size_t)(mt*16 + l15)*512 + ks*32 + quad*8);
      #pragma unroll
      for (int nti = 0; nti < 2; ++nti)
        acc[mt][nti] = __builtin_amdgcn_mfma_f32_16x16x32_bf16(a, bfr[nti], acc[mt][nti], 0, 0, 0);
    }
  }
  #pragma unroll
  for (int mt = 0; mt < 16; ++mt){
    int d0 = mt*16 + quad*4;
    #pragma unroll
    for (int nti = 0; nti < 2; ++nti){
      int tok = t0 + (nt0+nti)*16 + l15;
      size_t o = ((size_t)b*32768 + tok)*256 + d0;
      float r0,r1,r2,r3;
      if (f){
        short4 rv = *(const short4*)((const bf16*)u + o);
        r0 = bits2f((u16)rv.x); r1 = bits2f((u16)rv.y); r2 = bits2f((u16)rv.z); r3 = bits2f((u16)rv.w);
      } else {
        float4 rv = *(const float4*)((const float*)u + o);
        r0 = rv.x; r1 = rv.y; r2 = rv.z; r3 = rv.w;
      }
      float y0 = r0 + smg[d0+0]*(acc[mt][nti][0] + sbb[d0+0]);
      float y1 = r1 + smg[d0+1]*(acc[mt][nti][1] + sbb[d0+1]);
      float y2 = r2 + smg[d0+2]*(acc[mt][nti][2] + sbb[d0+2]);
      float y3 = r3 + smg[d0+3]*(acc[mt][nti][3] + sbb[d0+3]);
      if (f) *(short4*)((bf16*)outv + o) = pack4(y0,y1,y2,y3);
      else   *(float4*)((float*)outv + o) = (float4){y0,y1,y2,y3};
    }
  }
}

// ======== k_ffn2: coalesced LN + MFMA FFN + staged epilogue, in place ======
__global__ __launch_bounds__(256) void k_ffn2(
    const float* __restrict__ mod,
    const u16* __restrict__ w1f,
    const float* __restrict__ b1c,
    const u16* __restrict__ w2f,
    const float* __restrict__ b2c,
    void* __restrict__ outv,
    const int* __restrict__ flag){
  __shared__ __align__(16) u16 u2s[64][264];
  __shared__ __align__(16) u16 hs[64][136];
  __shared__ float smod_sh[256], smod_sc[256], smod_g[256], sb2[256];
  __shared__ float r1[64][4], r2[64][4], mv[64], rs[64];
  int f = *flag;
  int tid = threadIdx.x;
  int t0 = blockIdx.x*64; int bb = t0 >> 15;
  smod_sh[tid] = mod[bb*1536 + 768 + tid];
  smod_sc[tid] = mod[bb*1536 + 1024 + tid];
  smod_g[tid]  = mod[bb*1536 + 1280 + tid];
  sb2[tid] = b2c[tid];
  // phase 1: coalesced load u1 tile -> bf16 LDS
  for (int it = 0; it < 16; ++it){
    int idx = it*256 + tid;
    int tok = idx >> 6, c4 = idx & 63;
    short4 v4;
    if (f){
      v4 = *(const short4*)((const bf16*)outv + ((size_t)(t0+tok))*256 + c4*4);
    } else {
      float4 fv = ((const float4*)outv)[((size_t)(t0+tok))*64 + c4];
      v4 = pack4(fv.x, fv.y, fv.z, fv.w);
    }
    *(short4*)&u2s[tok][c4*4] = v4;
  }
  __syncthreads();
  // phase 2: stats
  {
    int tok = tid >> 2, part = tid & 3;
    float s1 = 0.f, s2 = 0.f;
    for (int c4 = 0; c4 < 16; ++c4){
      short4 v4 = *(const short4*)&u2s[tok][part*64 + c4*4];
      float a = bits2f((u16)v4.x), b = bits2f((u16)v4.y),
            c = bits2f((u16)v4.z), d = bits2f((u16)v4.w);
      s1 += a+b+c+d; s2 += a*a+b*b+c*c+d*d;
    }
    r1[tok][part] = s1; r2[tok][part] = s2;
  }
  __syncthreads();
  if ((tid & 3) == 0){
    int tok = tid >> 2;
    float a1 = r1[tok][0]+r1[tok][1]+r1[tok][2]+r1[tok][3];
    float a2 = r2[tok][0]+r2[tok][1]+r2[tok][2]+r2[tok][3];
    float mean = a1*(1.0f/256.0f);
    float var = a2*(1.0f/256.0f) - mean*mean;
    mv[tok] = mean; rs[tok] = rsqrtf(var + 1e-5f);
  }
  __syncthreads();
  // phase 3: modulate in place
  for (int it = 0; it < 16; ++it){
    int idx = it*256 + tid;
    int tok = idx >> 6, c4 = idx & 63;
    float mean = mv[tok], rstd = rs[tok];
    short4 v4 = *(const short4*)&u2s[tok][c4*4];
    u16 raw[4] = {(u16)v4.x,(u16)v4.y,(u16)v4.z,(u16)v4.w};
    float y[4];
    #pragma unroll
    for (int p = 0; p < 4; ++p){
      int c = c4*4 + p;
      y[p] = (bits2f(raw[p]) - mean)*rstd*(1.0f + smod_sc[c]) + smod_sh[c];
    }
    *(short4*)&u2s[tok][c4*4] = pack4(y[0],y[1],y[2],y[3]);
  }
  __syncthreads();
  // phase 4: MFMA
  int wave = tid >> 6, lane = tid & 63;
  int quad = lane >> 4, l15 = lane & 15;
  int mrow = wave*16;
  f32x4 acc2[16];
  #pragma unroll
  for (int nt = 0; nt < 16; ++nt) acc2[nt] = (f32x4){0.f,0.f,0.f,0.f};
  for (int hc = 0; hc < 8; ++hc){
    f32x4 acc1[8];
    #pragma unroll
    for (int nt = 0; nt < 8; ++nt) acc1[nt] = (f32x4){0.f,0.f,0.f,0.f};
    #pragma unroll
    for (int ks = 0; ks < 8; ++ks){
      short8 a = *(const short8*)&u2s[mrow + l15][ks*32 + quad*8];
      #pragma unroll
      for (int nt = 0; nt < 8; ++nt){
        short8 bfr = *(const short8*)&w1f[((((size_t)(hc*8 + nt))*8 + ks)*64 + lane)*8];
        acc1[nt] = __builtin_amdgcn_mfma_f32_16x16x32_bf16(a, bfr, acc1[nt], 0, 0, 0);
      }
    }
    #pragma unroll
    for (int nt = 0; nt < 8; ++nt){
      int hid = nt*16 + l15;
      float bb1 = b1c[hc*128 + hid];
      #pragma unroll
      for (int r = 0; r < 4; ++r){
        int tokr = mrow + quad*4 + r;
        hs[tokr][hid] = f2bits(gelu_f(acc1[nt][r] + bb1));
      }
    }
    __syncthreads();
    #pragma unroll
    for (int ks = 0; ks < 4; ++ks){
      short8 a2 = *(const short8*)&hs[mrow + l15][ks*32 + quad*8];
      #pragma unroll
      for (int nt = 0; nt < 16; ++nt){
        short8 bfr = *(const short8*)&w2f[((((size_t)nt)*32 + hc*4 + ks)*64 + lane)*8];
        acc2[nt] = __builtin_amdgcn_mfma_f32_16x16x32_bf16(a2, bfr, acc2[nt], 0, 0, 0);
      }
    }
    __syncthreads();
  }
  // phase 5: staged epilogue, two 128-col halves through hs
  for (int half = 0; half < 2; ++half){
    #pragma unroll
    for (int nt2 = 0; nt2 < 8; ++nt2){
      int nt = half*8 + nt2;
      int ncol = nt2*16 + l15;
      #pragma unroll
      for (int r = 0; r < 4; ++r)
        hs[mrow + quad*4 + r][ncol] = f2bits(acc2[nt][r]);
    }
    __syncthreads();
    for (int it = 0; it < 8; ++it){
      int idx = it*256 + tid;            // 2048 short4 groups: 64 tok x 32
      int tok = idx >> 5, c4 = idx & 31;
      int n0 = half*128 + c4*4;
      short4 yv = *(const short4*)&hs[tok][c4*4];
      float y[4] = {bits2f((u16)yv.x), bits2f((u16)yv.y), bits2f((u16)yv.z), bits2f((u16)yv.w)};
      size_t o = ((size_t)(t0+tok))*256 + n0;
      float r0,r1_,r2_,r3;
      if (f){
        short4 rv = *(const short4*)((const bf16*)outv + o);
        r0 = bits2f((u16)rv.x); r1_ = bits2f((u16)rv.y); r2_ = bits2f((u16)rv.z); r3 = bits2f((u16)rv.w);
      } else {
        float4 rv = *(const float4*)((const float*)outv + o);
        r0 = rv.x; r1_ = rv.y; r2_ = rv.z; r3 = rv.w;
      }
      float o0 = r0 + smod_g[n0+0]*(y[0] + sb2[n0+0]);
      float o1 = r1_ + smod_g[n0+1]*(y[1] + sb2[n0+1]);
      float o2 = r2_ + smod_g[n0+2]*(y[2] + sb2[n0+2]);
      float o3 = r3 + smod_g[n0+3]*(y[3] + sb2[n0+3]);
      if (f) *(short4*)((bf16*)outv + o) = pack4(o0,o1,o2,o3);
      else   *(float4*)((float*)outv + o) = (float4){o0,o1,o2,o3};
    }
    __syncthreads();
  }
}

extern "C" void kernel_launch(void* const* d_in, const int* in_sizes, int n_in,
                              void* d_out, int out_size, void* d_ws, size_t ws_size,
                              hipStream_t stream){
  (void)n_in; (void)out_size; (void)ws_size;

  char* p = (char*)d_ws;
  auto alloc = [&](size_t bytes)->void*{
    void* r = (void*)p; p += (bytes + 255) & ~(size_t)255; return r;
  };

  int* flag = (int*)alloc(4);
  float* cin[28];
  cin[0] = nullptr;
  for (int i = 1; i < 28; ++i) cin[i] = (float*)alloc((size_t)in_sizes[i]*4);

  float* mod  = (float*)alloc((size_t)4*1536*4);
  float* lw   = (float*)alloc((size_t)128*4);
  float* redx = (float*)alloc((size_t)4*256*256*4);
  float* redy = (float*)alloc((size_t)4*128*256*4);
  float* tx   = (float*)alloc((size_t)4*256*256*4);
  float* hx   = (float*)alloc((size_t)4*256*256*4);
  float* uxb  = (float*)alloc((size_t)4*256*128*4);
  float* ty   = (float*)alloc((size_t)4*128*256*4);
  float* hy   = (float*)alloc((size_t)4*128*256*4);
  float* uyb  = (float*)alloc((size_t)4*128*128*4);
  float* qkx  = (float*)alloc((size_t)4*256*1024*4);
  float* qky  = (float*)alloc((size_t)4*128*1024*4);
  float* radx = (float*)alloc((size_t)8*256*256*4);
  float* rady = (float*)alloc((size_t)8*128*128*4);
  u16* kxb = (u16*)alloc((size_t)32*256*256*2);
  u16* kyb = (u16*)alloc((size_t)32*128*128*2);
  u16* w1f = (u16*)alloc((size_t)256*1024*2);
  u16* w2f = (u16*)alloc((size_t)1024*256*2);
  u16* WvT = (u16*)alloc((size_t)512*256*2);
  u16* WmT = (u16*)alloc((size_t)256*512*2);
  u16* um    = (u16*)alloc((size_t)NTOK*256*2);        // 67 MB
  u16* slotV = (u16*)alloc((size_t)8*2097152*2);       // 33.5 MB
  u16* slotP = (u16*)alloc((size_t)8*2097152*2);       // 33.5 MB

  const void* u = d_in[0];

  k_detect<<<1, 1, 0, stream>>>(d_in[3], flag);
  for (int i = 1; i < 28; ++i){
    int n = in_sizes[i];
    int blocks = (n + 255)/256; if (blocks > 1024) blocks = 1024;
    k_cvt<<<blocks, 256, 0, stream>>>(d_in[i], cin[i], n, flag);
  }
  k_wprep<<<1024, 256, 0, stream>>>(cin[24], w1f, 8, 1024, 256*1024);
  k_wprep<<<1024, 256, 0, stream>>>(cin[26], w2f, 32, 256, 1024*256);
  k_wtrans<<<512, 256, 0, stream>>>(cin[7],  WvT, 256, 512);   // to_v_w
  k_wtrans<<<512, 256, 0, stream>>>(cin[22], WmT, 512, 256);   // merge_w

  k_mod<<<24, 256, 0, stream>>>(cin[4], cin[5], cin[6], mod);
  k_lw<<<1, 128, 0, stream>>>(cin[1], lw);
  k_um2<<<NTOK/64, 256, 0, stream>>>(u, mod, um, flag);
  k_redx<<<1024, 256, 0, stream>>>(um, lw, redx);
  k_redy<<<512, 256, 0, stream>>>(um, redy);
  gemm_row<<<1024, 256, 0, stream>>>(redx, cin[8],  nullptr, tx,  256, 256, 0);
  gemm_row<<<1024, 256, 0, stream>>>(tx,   cin[9],  cin[10], hx,  256, 256, 1);
  gemm_row<<<1024, 256, 0, stream>>>(hx,   cin[11], cin[12], uxb, 256, 128, 0);
  gemm_row<<<1024, 256, 0, stream>>>(uxb,  cin[18], nullptr, qkx, 128, 1024, 0);
  gemm_row<<<512, 256, 0, stream>>>(redy, cin[13], nullptr, ty,  256, 256, 0);
  gemm_row<<<512, 256, 0, stream>>>(ty,   cin[14], cin[15], hy,  256, 256, 1);
  gemm_row<<<512, 256, 0, stream>>>(hy,   cin[16], cin[17], uyb, 256, 128, 0);
  gemm_row<<<512, 256, 0, stream>>>(uyb,  cin[19], nullptr, qky, 128, 1024, 0);
  k_radial<<<(8*256*256)/256, 256, 0, stream>>>(cin[3], cin[20], radx, 256);
  k_radial<<<(8*128*128)/256, 256, 0, stream>>>(cin[2], cin[21], rady, 128);
  k_attn<<<4*8*256, 256, (64+256)*4, stream>>>(qkx, radx, kxb, 256);
  k_attn<<<4*8*128, 128, (64+128)*4, stream>>>(qky, rady, kyb, 128);

  for (int b = 0; b < 4; ++b){
    u16* vTb  = slotV;   // vT[h][tok][c]
    u16* phb  = slotP;   // phi[h][i][c*256+m]
    u16* outt = slotV;   // OUTt[h][l][i*64+c]  (vT dead)
    u16* gnb  = slotP;   // gn[tok][h*64+c]     (phi dead)
    k_v2    <<<512, 256, 0, stream>>>(um, WvT, vTb, b);
    k_phi1b <<<512, 256, 0, stream>>>(kyb, vTb, phb, b);
    k_phi2b <<<512, 256, 0, stream>>>(kxb, phb, outt, b);
    k_gnb   <<<2048, 256, 0, stream>>>(outt, gnb);
    k_mergeb<<<256, 256, 0, stream>>>(gnb, WmT, cin[23], mod, u, d_out, flag, b);
  }
  k_ffn2<<<NTOK/64, 256, 0, stream>>>(mod, w1f, cin[25], w2f, cin[27], d_out, flag);
}